// Round 28
// baseline (20.064 us; speedup 1.0000x reference)
//
#include <hip/hip_runtime.h>
#include <hip/hip_bf16.h>

#define DD 256
#define NROWS 16384

typedef float f32x4 __attribute__((ext_vector_type(4)));
typedef __bf16 bf16x4 __attribute__((ext_vector_type(4)));
typedef __bf16 bf16x8 __attribute__((ext_vector_type(8)));

__device__ __forceinline__ bf16x8 cvt8(f32x4 lo, f32x4 hi) {
  bf16x8 v;
#pragma unroll
  for (int j = 0; j < 4; ++j) {
    v[j] = (__bf16)lo[j];
    v[4 + j] = (__bf16)hi[j];
  }
  return v;
}

// ---------------------------------------------------------------------------
// K1: Wc = Wout @ Wv (bf16), bc = bout + Wout @ bv.  [R19 version VERBATIM]
// ---------------------------------------------------------------------------
__global__ __launch_bounds__(1024) void wc_bc_kernel(
    const float* __restrict__ Wqkv, const float* __restrict__ bqkv,
    const float* __restrict__ Wout, const float* __restrict__ bout,
    __bf16* __restrict__ Wc, float* __restrict__ bc) {
  __shared__ float part[16][4][64];  // 16 KiB
  __shared__ float red[4];
  const int b = blockIdx.x;
  const int i0 = (b >> 2) * 4;
  const int qc = b & 3;
  const int c0 = qc * 64;
  const int t = threadIdx.x;
  const int w = t >> 6, l = t & 63;
  const float* __restrict__ Wv = Wqkv + 2 * DD * DD;
  const float* __restrict__ bv = bqkv + 2 * DD;

  float wo[4][16];
#pragma unroll
  for (int r = 0; r < 4; ++r)
#pragma unroll
    for (int jj = 0; jj < 16; ++jj)
      wo[r][jj] = Wout[(size_t)(i0 + r) * DD + w * 16 + jj];

  float acc0 = 0.f, acc1 = 0.f, acc2 = 0.f, acc3 = 0.f;
  const float* wvp = Wv + (size_t)(w * 16) * DD + c0 + l;
#pragma unroll
  for (int jj = 0; jj < 16; ++jj) {
    const float wv = wvp[(size_t)jj * DD];
    acc0 += wo[0][jj] * wv;
    acc1 += wo[1][jj] * wv;
    acc2 += wo[2][jj] * wv;
    acc3 += wo[3][jj] * wv;
  }
  part[w][0][l] = acc0;
  part[w][1][l] = acc1;
  part[w][2][l] = acc2;
  part[w][3][l] = acc3;

  if (qc == 0 && t < 256) {
    const int r = t >> 6, ll = t & 63;
    float p = 0.f;
#pragma unroll
    for (int k = 0; k < 4; ++k)
      p += Wout[(size_t)(i0 + r) * DD + k * 64 + ll] * bv[k * 64 + ll];
#pragma unroll
    for (int off = 32; off > 0; off >>= 1) p += __shfl_down(p, off);
    if (ll == 0) red[r] = p;
  }
  __syncthreads();
  if (t < 256) {
    const int r = t >> 6, ll = t & 63;
    float s = 0.f;
#pragma unroll
    for (int k = 0; k < 16; ++k) s += part[k][r][ll];
    Wc[(size_t)(i0 + r) * DD + c0 + ll] = (__bf16)s;
    if (qc == 0 && ll == 0) bc[i0 + r] = bout[i0 + r] + red[r];
  }
}

// ---------------------------------------------------------------------------
// K2: out = x + x @ Wc^T + bc.  [TWO-barrier minimal schedule: R18's
// one-compute-window + R24's coalesced stores + R26's af amortization.
// Stage all 64 rows -> sync -> all 4 tiles back-to-back into a full 64-row
// osd (32 ds_read + 32 MFMA, no intervening barriers = max scheduler
// freedom) -> sync -> one store pass (4 full-1KB-row insts per wave).
// LDS 32+64 = 96KB (1 block/CU -- grid 256 gives 1/CU anyway). All
// addressing byte-identical to verified R24/R26 pieces.]
// ---------------------------------------------------------------------------
__global__ __launch_bounds__(1024, 2) void knn_attn_main(
    const float* __restrict__ x, const __bf16* __restrict__ Wc,
    const float* __restrict__ bc, float* __restrict__ out) {
  __shared__ __bf16 xs[64 * DD];  // 32 KiB: all 64 rows, swizzled
  __shared__ float osd[64 * DD];  // 64 KiB: all 64 output rows, swizzled

  const int t = threadIdx.x;
  const int w = t >> 6, l = t & 63;  // 16 waves
  const int Rblk = blockIdx.x * 64;
  const int xrow = l & 15, g4 = l >> 4;
  const int C0 = w * 16;  // this wave's 16 out-cols

  // Weight fragments (32 VGPR) + bias: loaded ONCE per block.
  bf16x8 af[8];
  {
    const __bf16* wrp = Wc + (size_t)(C0 + xrow) * DD + g4 * 8;
#pragma unroll
    for (int ks = 0; ks < 8; ++ks) af[ks] = *(const bf16x8*)(wrp + ks * 32);
  }
  const f32x4 bias = *(const f32x4*)(bc + C0 + g4 * 4);  // incl. bout

  // Stage all 64 rows: thread t -> row sr = t>>4, 16 floats at seg sc = t&15.
  {
    const int sr = t >> 4, sc = t & 15;
    const int ssw = (sr & 7) << 4;
    const int sbase = sr * 512 + sc * 32;
    const float* s0 = x + (size_t)(Rblk + sr) * DD + sc * 16;
    f32x4 a = *(const f32x4*)(s0 + 0);
    f32x4 b = *(const f32x4*)(s0 + 4);
    f32x4 c = *(const f32x4*)(s0 + 8);
    f32x4 d = *(const f32x4*)(s0 + 12);
    *(bf16x8*)((char*)xs + ((sbase + 0) ^ ssw)) = cvt8(a, b);
    *(bf16x8*)((char*)xs + ((sbase + 16) ^ ssw)) = cvt8(c, d);
  }
  __syncthreads();  // barrier 1: xs ready

  const int ocol = C0 + g4 * 4;
  const int xsw = (xrow & 7) << 4;  // == (lrow&7)<<4, tiles are 16 rows

  // All 4 tiles, zero intervening barriers (osd rows disjoint per tile).
#pragma unroll
  for (int i = 0; i < 4; ++i) {
    const int lrow = i * 16 + xrow;
    bf16x8 xf[8];
#pragma unroll
    for (int ks = 0; ks < 8; ++ks)
      xf[ks] = *(const bf16x8*)((const char*)xs +
                                ((lrow * 512 + ks * 64 + g4 * 16) ^ xsw));
    f32x4 acc = {0.f, 0.f, 0.f, 0.f};
#pragma unroll
    for (int ks = 0; ks < 8; ++ks)
      acc = __builtin_amdgcn_mfma_f32_16x16x32_bf16(af[ks], xf[ks], acc, 0, 0, 0);
    // D: col(l&15)=x-row, rowquad g4*4+reg = out-col (verified R5..R27).
    bf16x4 xr4 = *(const bf16x4*)((const char*)xs +
                                  ((lrow * 512 + ocol * 2) ^ xsw));
    f32x4 xres;
#pragma unroll
    for (int j = 0; j < 4; ++j) xres[j] = (float)xr4[j];
    f32x4 o = acc + xres + bias;
    *(f32x4*)((char*)osd + (lrow * 1024 + ((ocol * 4) ^ xsw))) = o;
  }
  __syncthreads();  // barrier 2: osd complete

  // Store pass: wave w stores rows {w, 16+w, 32+w, 48+w}; one full
  // contiguous 1KB row per instruction; XOR unwound (physical->logical).
#pragma unroll
  for (int j = 0; j < 4; ++j) {
    const int r = j * 16 + w;
    const int cbp = (l * 16) ^ ((w & 7) << 4);  // (r&7)==(w&7): j*16 == 0 mod 8
    f32x4 ov = *(const f32x4*)((const char*)osd + (r * 1024 + cbp));
    __builtin_nontemporal_store(
        ov, (f32x4*)(out + (size_t)(Rblk + r) * DD + l * 4));
  }
}

extern "C" void kernel_launch(void* const* d_in, const int* in_sizes, int n_in,
                              void* d_out, int out_size, void* d_ws, size_t ws_size,
                              hipStream_t stream) {
  const float* x = (const float*)d_in[0];
  const float* Wqkv = (const float*)d_in[1];
  const float* bqkv = (const float*)d_in[2];
  const float* Wout = (const float*)d_in[3];
  const float* bout = (const float*)d_in[4];
  float* out = (float*)d_out;

  __bf16* Wc = (__bf16*)d_ws;                                   // 128 KiB
  float* bc = (float*)((char*)d_ws + DD * DD * sizeof(__bf16)); // +1 KiB

  wc_bc_kernel<<<DD, 1024, 0, stream>>>(Wqkv, bqkv, Wout, bout, Wc, bc);
  knn_attn_main<<<NROWS / 64, 1024, 0, stream>>>(x, Wc, bc, out);
}

// Round 29
// 18.750 us; speedup vs baseline: 1.0701x; 1.0701x over previous
//
#include <hip/hip_runtime.h>
#include <hip/hip_bf16.h>

#define DD 256
#define NROWS 16384

typedef float f32x4 __attribute__((ext_vector_type(4)));
typedef __bf16 bf16x4 __attribute__((ext_vector_type(4)));
typedef __bf16 bf16x8 __attribute__((ext_vector_type(8)));

__device__ __forceinline__ bf16x8 cvt8(f32x4 lo, f32x4 hi) {
  bf16x8 v;
#pragma unroll
  for (int j = 0; j < 4; ++j) {
    v[j] = (__bf16)lo[j];
    v[4 + j] = (__bf16)hi[j];
  }
  return v;
}

// ---------------------------------------------------------------------------
// K1: Wc = Wout @ Wv (bf16), bc = bout + Wout @ bv.  [R19 version VERBATIM]
// ---------------------------------------------------------------------------
__global__ __launch_bounds__(1024) void wc_bc_kernel(
    const float* __restrict__ Wqkv, const float* __restrict__ bqkv,
    const float* __restrict__ Wout, const float* __restrict__ bout,
    __bf16* __restrict__ Wc, float* __restrict__ bc) {
  __shared__ float part[16][4][64];  // 16 KiB
  __shared__ float red[4];
  const int b = blockIdx.x;
  const int i0 = (b >> 2) * 4;
  const int qc = b & 3;
  const int c0 = qc * 64;
  const int t = threadIdx.x;
  const int w = t >> 6, l = t & 63;
  const float* __restrict__ Wv = Wqkv + 2 * DD * DD;
  const float* __restrict__ bv = bqkv + 2 * DD;

  float wo[4][16];
#pragma unroll
  for (int r = 0; r < 4; ++r)
#pragma unroll
    for (int jj = 0; jj < 16; ++jj)
      wo[r][jj] = Wout[(size_t)(i0 + r) * DD + w * 16 + jj];

  float acc0 = 0.f, acc1 = 0.f, acc2 = 0.f, acc3 = 0.f;
  const float* wvp = Wv + (size_t)(w * 16) * DD + c0 + l;
#pragma unroll
  for (int jj = 0; jj < 16; ++jj) {
    const float wv = wvp[(size_t)jj * DD];
    acc0 += wo[0][jj] * wv;
    acc1 += wo[1][jj] * wv;
    acc2 += wo[2][jj] * wv;
    acc3 += wo[3][jj] * wv;
  }
  part[w][0][l] = acc0;
  part[w][1][l] = acc1;
  part[w][2][l] = acc2;
  part[w][3][l] = acc3;

  if (qc == 0 && t < 256) {
    const int r = t >> 6, ll = t & 63;
    float p = 0.f;
#pragma unroll
    for (int k = 0; k < 4; ++k)
      p += Wout[(size_t)(i0 + r) * DD + k * 64 + ll] * bv[k * 64 + ll];
#pragma unroll
    for (int off = 32; off > 0; off >>= 1) p += __shfl_down(p, off);
    if (ll == 0) red[r] = p;
  }
  __syncthreads();
  if (t < 256) {
    const int r = t >> 6, ll = t & 63;
    float s = 0.f;
#pragma unroll
    for (int k = 0; k < 16; ++k) s += part[k][r][ll];
    Wc[(size_t)(i0 + r) * DD + c0 + ll] = (__bf16)s;
    if (qc == 0 && ll == 0) bc[i0 + r] = bout[i0 + r] + red[r];
  }
}

// ---------------------------------------------------------------------------
// K2: out = x + x @ Wc^T + bc.  [R26 version VERBATIM -- best measured
// (18.78us). Two 32-row tiles per block (rows [bid*64,+64), grid 256) so
// af[8] loads once per block (32 MB aggregate Wc traffic); x staged once
// per row; tile-1 globals issue under tile-0 compute; coalesced store pass
// (full 1KB row per wave instruction, XOR unwound). LDS 48KB.]
// ---------------------------------------------------------------------------
__global__ __launch_bounds__(1024, 2) void knn_attn_main(
    const float* __restrict__ x, const __bf16* __restrict__ Wc,
    const float* __restrict__ bc, float* __restrict__ out) {
  __shared__ __bf16 xs[32 * DD];  // 16 KiB x tile, swizzled
  __shared__ float osd[32 * DD];  // 32 KiB output staging, swizzled

  const int t = threadIdx.x;
  const int w = t >> 6, l = t & 63;  // 16 waves
  const int Rblk = blockIdx.x * 64;
  const int xrow = l & 15, g4 = l >> 4;
  const int C0 = w * 16;  // this wave's 16 out-cols

  // Weight fragments (32 VGPR) + bias: loaded ONCE per block.
  bf16x8 af[8];
  {
    const __bf16* wrp = Wc + (size_t)(C0 + xrow) * DD + g4 * 8;
#pragma unroll
    for (int ks = 0; ks < 8; ++ks) af[ks] = *(const bf16x8*)(wrp + ks * 32);
  }
  const f32x4 bias = *(const f32x4*)(bc + C0 + g4 * 4);  // incl. bout

  // Staging geometry (R24): thread t -> row sr = t>>5, 8 floats at sc = t&31.
  const int sr = t >> 5, sc = t & 31;
  const int ssw = (sr & 7) << 4;

  {  // stage tile 0
    const float* s0 = x + (size_t)(Rblk + sr) * DD + sc * 8;
    f32x4 a = *(const f32x4*)(s0);
    f32x4 b = *(const f32x4*)(s0 + 4);
    *(bf16x8*)((char*)xs + ((sr * 512 + sc * 16) ^ ssw)) = cvt8(a, b);
  }
  __syncthreads();

  for (int rt = 0; rt < 2; ++rt) {
    f32x4 na, nb;
    if (rt == 0) {  // tile-1 loads fly under tile-0 compute
      const float* s1 = x + (size_t)(Rblk + 32 + sr) * DD + sc * 8;
      na = *(const f32x4*)(s1);
      nb = *(const f32x4*)(s1 + 4);
    }

    // Compute both 16-row sub-tiles -> swizzled osd.
#pragma unroll
    for (int st = 0; st < 2; ++st) {
      const int lrow = st * 16 + xrow;
      const int lsw = (lrow & 7) << 4;
      bf16x8 xf[8];
#pragma unroll
      for (int ks = 0; ks < 8; ++ks)
        xf[ks] = *(const bf16x8*)((const char*)xs +
                                  ((lrow * 512 + ks * 64 + g4 * 16) ^ lsw));
      f32x4 acc = {0.f, 0.f, 0.f, 0.f};
#pragma unroll
      for (int ks = 0; ks < 8; ++ks)
        acc = __builtin_amdgcn_mfma_f32_16x16x32_bf16(af[ks], xf[ks], acc, 0, 0, 0);
      // D: col(l&15)=x-row, rowquad g4*4+reg = out-col (verified R5..R28).
      const int ocol = C0 + g4 * 4;
      bf16x4 xr4 = *(const bf16x4*)((const char*)xs +
                                    ((lrow * 512 + ocol * 2) ^ lsw));
      f32x4 xres;
#pragma unroll
      for (int j = 0; j < 4; ++j) xres[j] = (float)xr4[j];
      f32x4 o = acc + xres + bias;
      *(f32x4*)((char*)osd + (lrow * 1024 + ((ocol * 4) ^ lsw))) = o;
    }
    __syncthreads();  // xs reads done; osd writes done

    if (rt == 0)  // publish tile 1 into xs (readers finished above)
      *(bf16x8*)((char*)xs + ((sr * 512 + sc * 16) ^ ssw)) = cvt8(na, nb);

    // Coalesced store pass: full 1KB row per instruction, XOR unwound.
#pragma unroll
    for (int j = 0; j < 2; ++j) {
      const int r = j * 16 + w;
      const int cbp = (l * 16) ^ ((r & 7) << 4);  // physical LDS byte
      f32x4 o = *(const f32x4*)((const char*)osd + (r * 1024 + cbp));
      __builtin_nontemporal_store(
          o, (f32x4*)(out + (size_t)(Rblk + rt * 32 + r) * DD + l * 4));
    }

    if (rt == 0) __syncthreads();  // xs writes visible; osd reads done
  }
}

extern "C" void kernel_launch(void* const* d_in, const int* in_sizes, int n_in,
                              void* d_out, int out_size, void* d_ws, size_t ws_size,
                              hipStream_t stream) {
  const float* x = (const float*)d_in[0];
  const float* Wqkv = (const float*)d_in[1];
  const float* bqkv = (const float*)d_in[2];
  const float* Wout = (const float*)d_in[3];
  const float* bout = (const float*)d_in[4];
  float* out = (float*)d_out;

  __bf16* Wc = (__bf16*)d_ws;                                   // 128 KiB
  float* bc = (float*)((char*)d_ws + DD * DD * sizeof(__bf16)); // +1 KiB

  wc_bc_kernel<<<DD, 1024, 0, stream>>>(Wqkv, bqkv, Wout, bout, Wc, bc);
  knn_attn_main<<<NROWS / 64, 1024, 0, stream>>>(x, Wc, bc, out);
}